// Round 10
// baseline (138.709 us; speedup 1.0000x reference)
//
#include <hip/hip_runtime.h>
#include <math.h>

#define NB 8
#define CIN 256
#define SEQ 1024
#define NH 8
#define DH 64
#define HID 512
#define OQKV 1536

typedef __attribute__((ext_vector_type(8))) short short8;
typedef __attribute__((ext_vector_type(4))) short short4v;
typedef __attribute__((ext_vector_type(4))) float float4v;

static __device__ inline short f2bf(float x) {  // RNE
    union { float f; unsigned u; } c; c.f = x;
    unsigned r = (c.u + 0x7FFFu + ((c.u >> 16) & 1u)) >> 16;
    return (short)r;
}
static __device__ inline float bf2f(short h) {
    union { unsigned u; float f; } c; c.u = ((unsigned)(unsigned short)h) << 16;
    return c.f;
}

// ============ K0: all input packs + ssq zero, one launch ====================
__global__ __launch_bounds__(256) void pack_all(const float* __restrict__ x,
                                                const float* __restrict__ w_qkv,
                                                const float* __restrict__ w_out,
                                                short* __restrict__ xp,
                                                short* __restrict__ wqp,
                                                short* __restrict__ wpk,
                                                float* __restrict__ ssq) {
    const int t = threadIdx.x, lane = t & 63, wv = t >> 6;
    const int bx = blockIdx.x;
    const int c = lane & 15, q = lane >> 4;
    if (bx < 1024) {
        const int fid = bx * 4 + wv;  // 0..4095
        const int b = fid >> 9, kt = (fid >> 6) & 7, nt = fid & 63;
        const float* src = x + ((size_t)(b * 256 + kt * 32 + q * 8)) * SEQ + nt * 16 + c;
        short8 v;
#pragma unroll
        for (int e = 0; e < 8; ++e) v[e] = f2bf(src[(size_t)e * SEQ]);
        *(short8*)(xp + (size_t)fid * 512 + lane * 8) = v;
    } else if (bx < 1216) {
        const int fid = (bx - 1024) * 4 + wv;  // 0..767
        const int m = (fid >> 3) * 16 + c;
        const int k0 = (fid & 7) * 32 + q * 8;
        const float* p = w_qkv + (size_t)m * CIN + k0;
        float4v lo = *(const float4v*)p;
        float4v hi = *(const float4v*)(p + 4);
        short8 v;
#pragma unroll
        for (int e = 0; e < 4; ++e) { v[e] = f2bf(lo[e]); v[4 + e] = f2bf(hi[e]); }
        *(short8*)(wqp + (size_t)fid * 512 + lane * 8) = v;
    } else if (bx < 1280) {
        const int fid = (bx - 1216) * 4 + wv;  // 0..255
        const int m = (fid >> 4) * 16 + c;
        const int k0 = (fid & 15) * 32 + q * 8;
        const float* p = w_out + (size_t)m * HID + k0;
        float4v lo = *(const float4v*)p;
        float4v hi = *(const float4v*)(p + 4);
        short8 v;
#pragma unroll
        for (int e = 0; e < 4; ++e) { v[e] = f2bf(lo[e]); v[4 + e] = f2bf(hi[e]); }
        *(short8*)(wpk + (size_t)fid * 512 + lane * 8) = v;
    } else {
        float4v z = (float4v){0.f, 0.f, 0.f, 0.f};
#pragma unroll
        for (int k = 0; k < 8; ++k) *((float4v*)ssq + t * 8 + k) = z;
    }
}

// ============ K1: qkv projection — LDS-free barrier-free frag GEMM =========
// 1D grid 768, XCD swizzle: b = id&7 (all 96 blocks of a batch share one XCD;
// xp[b] 4MB + wqp 0.8MB ~ L2-resident). Wave zh = zone*8+h owns 64 m x 64 s.
__global__ __launch_bounds__(256) void qkv_frag(const short* __restrict__ xp,
                                                const short* __restrict__ wqp,
                                                short* __restrict__ qp,
                                                short* __restrict__ kp,
                                                short* __restrict__ vp,
                                                float* __restrict__ ssq) {
    const int t = threadIdx.x, lane = t & 63, wv = t >> 6;
    const int c = lane & 15, q = lane >> 4;
    const int id = blockIdx.x;
    const int b = id & 7, r_ = id >> 3;          // XCD = b
    const int nt0 = (r_ & 15) * 4;               // 4 n-tiles = 64 s
    const int zh = (r_ >> 4) * 4 + wv;           // 0..23
    const int zone = zh >> 3, h = zh & 7;
    const int bh = b * 8 + h;

    const short* bp = xp + ((size_t)b * 512 + nt0) * 512 + lane * 8;
    const short* ap = wqp + (size_t)zh * 32 * 512 + lane * 8;

    float4v acc[4][4];
#pragma unroll
    for (int i = 0; i < 4; ++i)
#pragma unroll
        for (int j = 0; j < 4; ++j) acc[i][j] = (float4v){0.f, 0.f, 0.f, 0.f};

#pragma unroll 2
    for (int kt = 0; kt < 8; ++kt) {
        short8 bfr[4], af[4];
#pragma unroll
        for (int j = 0; j < 4; ++j)
            bfr[j] = *(const short8*)(bp + ((size_t)kt * 64 + j) * 512);
#pragma unroll
        for (int i = 0; i < 4; ++i)
            af[i] = *(const short8*)(ap + (size_t)(i * 8 + kt) * 512);
        if (zone < 2) {
#pragma unroll
            for (int i = 0; i < 4; ++i)
#pragma unroll
                for (int j = 0; j < 4; ++j)
                    acc[i][j] = __builtin_amdgcn_mfma_f32_16x16x32_bf16(af[i], bfr[j],
                                                                        acc[i][j], 0, 0, 0);
        } else {
#pragma unroll
            for (int i = 0; i < 4; ++i)
#pragma unroll
                for (int j = 0; j < 4; ++j)
                    acc[i][j] = __builtin_amdgcn_mfma_f32_16x16x32_bf16(bfr[j], af[i],
                                                                        acc[i][j], 0, 0, 0);
        }
    }

    if (zone < 2) {
        // ---- RoPE: acc[0] rows d=q*4+r pair with acc[1] rows d+16 ----
#pragma unroll
        for (int r = 0; r < 4; ++r) {
            const int d = q * 4 + r;
            const float invf = exp2f(-(float)d * 0.83048202372184045f);  // 10000^(-d/16)
#pragma unroll
            for (int j = 0; j < 4; ++j) {
                float ang = (float)((nt0 + j) * 16 + c) * invf;
                float sn, cs;
                __sincosf(ang, &sn, &cs);
                float v0 = acc[0][j][r], v1 = acc[1][j][r];
                acc[0][j][r] = v0 * cs - v1 * sn;
                acc[1][j][r] = v1 * cs + v0 * sn;
            }
        }
        // ---- per-row ssq partials -> atomicAdd ----
        float* sq = ssq + (size_t)b * 1024 + zone * 512 + h * 64;
#pragma unroll
        for (int i = 0; i < 4; ++i)
#pragma unroll
            for (int r = 0; r < 4; ++r) {
                float val = 0.f;
#pragma unroll
                for (int j = 0; j < 4; ++j) val += acc[i][j][r] * acc[i][j][r];
#pragma unroll
                for (int o = 1; o < 16; o <<= 1) val += __shfl_xor(val, o, 64);
                if (c == 0) atomicAdd(&sq[i * 16 + q * 4 + r], val);
            }
        // ---- scatter roped (unnormalized) bf16, contiguous short4 ----
        short* dst = (zone ? kp : qp) + (size_t)bh * 65536;
        const int e0 = (q & 1) * 4;
#pragma unroll
        for (int i = 0; i < 4; ++i) {
            const int st = i >> 1;
            const int qp_ = (2 * i + (q >> 1)) & 3;
#pragma unroll
            for (int j = 0; j < 4; ++j) {
                const int slice = nt0 + j;
                short4v s4;
#pragma unroll
                for (int r = 0; r < 4; ++r) s4[r] = f2bf(acc[i][j][r]);
                *(short4v*)(dst + (((size_t)slice * 2 + st) * 64 + qp_ * 16 + c) * 8 + e0) = s4;
            }
        }
    } else {
        // ---- V (transposed tiles): s = (nt0+j)*16 + q*4 + r, d = i*16 + c ----
        short* dst = vp + (size_t)bh * 65536;
        const int e0 = (q & 1) * 4;
#pragma unroll
        for (int j = 0; j < 4; ++j) {
            const int jt = (nt0 + j) >> 1;
            const int qpart = ((nt0 + j) * 2 + (q >> 1)) & 3;
#pragma unroll
            for (int i = 0; i < 4; ++i) {
                short4v s4;
#pragma unroll
                for (int r = 0; r < 4; ++r) s4[r] = f2bf(acc[i][j][r]);
                *(short4v*)(dst + (((size_t)jt * 4 + i) * 64 + qpart * 16 + c) * 8 + e0) = s4;
            }
        }
    }
}

// ============ K2: attention — barrier-free, q-scale folded, 2 i-tiles ======
// 1D grid 512, XCD swizzle: bh = id&63 (8 it-blocks of a bh share id%8 ->
// one XCD; per-XCD K/V working set 8 bh x 256KB = 2MB < 4MB L2).
__global__ __launch_bounds__(256) void attn_mfma(const short* __restrict__ qp,
                                                 const short* __restrict__ kp,
                                                 const short* __restrict__ vp,
                                                 const float* __restrict__ ssq,
                                                 short* __restrict__ aop) {
    __shared__ __align__(16) short pt[4][16][40];  // per-wave P tile, 80B pitch
    const int t = threadIdx.x, lane = t & 63, wv = t >> 6;
    const int id = blockIdx.x;
    const int bh = id & 63, b = bh >> 3, h = bh & 7;
    const int it0 = ((id >> 6) * 4 + wv) * 2;  // 2 i-tiles per wave
    const int c = lane & 15, q = lane >> 4;

    // per-d q-scale: 10/(nq[d]*nk[d]), d = st*32 + q*8 + e
    const float* sq_q = ssq + (size_t)b * 1024 + h * 64;
    const float* sq_k = sq_q + 512;
    float scl[2][8];
#pragma unroll
    for (int st = 0; st < 2; ++st) {
        const int d0 = st * 32 + q * 8;
        float4v q0 = *(const float4v*)(sq_q + d0);
        float4v q1 = *(const float4v*)(sq_q + d0 + 4);
        float4v k0 = *(const float4v*)(sq_k + d0);
        float4v k1 = *(const float4v*)(sq_k + d0 + 4);
#pragma unroll
        for (int e = 0; e < 4; ++e) {
            scl[st][e] = 10.f * rsqrtf(q0[e] * k0[e]);
            scl[st][4 + e] = 10.f * rsqrtf(q1[e] * k1[e]);
        }
    }

    short8 aq[2][2];
#pragma unroll
    for (int u = 0; u < 2; ++u) {
        const short* qpb = qp + (size_t)bh * 65536 + (size_t)(it0 + u) * 1024 + lane * 8;
#pragma unroll
        for (int st = 0; st < 2; ++st) {
            short8 raw = *(const short8*)(qpb + st * 512);
#pragma unroll
            for (int e = 0; e < 8; ++e) aq[u][st][e] = f2bf(bf2f(raw[e]) * scl[st][e]);
        }
    }

    short8 ones;
#pragma unroll
    for (int e = 0; e < 8; ++e) ones[e] = (short)0x3F80;  // bf16(1.0)

    float4v acc[2][4], accS[2];
#pragma unroll
    for (int u = 0; u < 2; ++u) {
        accS[u] = (float4v){0.f, 0.f, 0.f, 0.f};
#pragma unroll
        for (int dt = 0; dt < 4; ++dt) acc[u][dt] = (float4v){0.f, 0.f, 0.f, 0.f};
    }

    for (int jt = 0; jt < 32; ++jt) {
        const short* kbb = kp + (size_t)bh * 65536 + (size_t)jt * 2048 + lane * 8;
        short8 bk00 = *(const short8*)kbb;
        short8 bk01 = *(const short8*)(kbb + 512);
        short8 bk10 = *(const short8*)(kbb + 1024);
        short8 bk11 = *(const short8*)(kbb + 1536);
        const short* vbb = vp + (size_t)bh * 65536 + (size_t)jt * 2048 + lane * 8;
        short8 bv0 = *(const short8*)vbb;
        short8 bv1 = *(const short8*)(vbb + 512);
        short8 bv2 = *(const short8*)(vbb + 1024);
        short8 bv3 = *(const short8*)(vbb + 1536);

#pragma unroll
        for (int u = 0; u < 2; ++u) {
            // S^T = K.Q'^T: C col axis = i
            float4v s0 = (float4v){0.f, 0.f, 0.f, 0.f};
            float4v s1 = (float4v){0.f, 0.f, 0.f, 0.f};
            s0 = __builtin_amdgcn_mfma_f32_16x16x32_bf16(bk00, aq[u][0], s0, 0, 0, 0);
            s0 = __builtin_amdgcn_mfma_f32_16x16x32_bf16(bk01, aq[u][1], s0, 0, 0, 0);
            s1 = __builtin_amdgcn_mfma_f32_16x16x32_bf16(bk10, aq[u][0], s1, 0, 0, 0);
            s1 = __builtin_amdgcn_mfma_f32_16x16x32_bf16(bk11, aq[u][1], s1, 0, 0, 0);

            // P^T = exp(S^T) -> truncate bf16 pairs -> per-wave LDS tile
            int* ptw = (int*)&pt[wv][c][0];
#pragma unroll
            for (int jh = 0; jh < 2; ++jh) {
                float4v s = jh ? s1 : s0;
                unsigned u0 = __float_as_uint(__expf(s[0]));
                unsigned u1 = __float_as_uint(__expf(s[1]));
                unsigned u2 = __float_as_uint(__expf(s[2]));
                unsigned u3 = __float_as_uint(__expf(s[3]));
                ptw[jh * 8 + q * 2]     = (int)((u1 & 0xFFFF0000u) | (u0 >> 16));
                ptw[jh * 8 + q * 2 + 1] = (int)((u3 & 0xFFFF0000u) | (u2 >> 16));
            }
            short8 ap = *(const short8*)&pt[wv][c][q * 8];  // P[i=c][j=q*8+e]

            // transposed PV: D[m=d][n=i]
            acc[u][0] = __builtin_amdgcn_mfma_f32_16x16x32_bf16(bv0, ap, acc[u][0], 0, 0, 0);
            acc[u][1] = __builtin_amdgcn_mfma_f32_16x16x32_bf16(bv1, ap, acc[u][1], 0, 0, 0);
            acc[u][2] = __builtin_amdgcn_mfma_f32_16x16x32_bf16(bv2, ap, acc[u][2], 0, 0, 0);
            acc[u][3] = __builtin_amdgcn_mfma_f32_16x16x32_bf16(bv3, ap, acc[u][3], 0, 0, 0);
            accS[u]   = __builtin_amdgcn_mfma_f32_16x16x32_bf16(ones, ap, accS[u], 0, 0, 0);
        }
    }

    // contiguous short4 stores into out_proj B-frag order
    short* ab = aop + (size_t)b * 524288;
    const int e0 = (q & 1) * 4;
#pragma unroll
    for (int u = 0; u < 2; ++u) {
        const int it = it0 + u;
        const float inv = 1.0f / accS[u][0];  // denominator for i = c
#pragma unroll
        for (int dt = 0; dt < 4; ++dt) {
            const int kt = h * 2 + (dt >> 1);
            const int ln = ((dt * 2 + (q >> 1)) & 3) * 16 + c;
            short4v s4;
#pragma unroll
            for (int r = 0; r < 4; ++r) s4[r] = f2bf(acc[u][dt][r] * inv);
            *(short4v*)(ab + (((size_t)kt * 64 + it) * 64 + ln) * 8 + e0) = s4;
        }
    }
}

// ============ K3: out projection — LDS-free, barrier-free frag GEMM =========
__global__ __launch_bounds__(256) void out_proj(const short* __restrict__ wp,
                                                const short* __restrict__ aop,
                                                const float* __restrict__ bias,
                                                float* __restrict__ out) {
    const int t = threadIdx.x, lane = t & 63, w = t >> 6;
    const int nt = blockIdx.x, b = blockIdx.y;
    const int c = lane & 15, q = lane >> 4;

    const short* bp = aop + ((size_t)b * 1024 + nt) * 512 + lane * 8;
    const short* ap = wp + (size_t)lane * 8;

    float4v acc[4];
#pragma unroll
    for (int i = 0; i < 4; ++i) acc[i] = (float4v){0.f, 0.f, 0.f, 0.f};

#pragma unroll 4
    for (int kt = 0; kt < 16; ++kt) {
        short8 bf_ = *(const short8*)(bp + (size_t)kt * 32768);
#pragma unroll
        for (int i = 0; i < 4; ++i) {
            short8 af = *(const short8*)(ap + (size_t)((w * 4 + i) * 16 + kt) * 512);
            acc[i] = __builtin_amdgcn_mfma_f32_16x16x32_bf16(af, bf_, acc[i], 0, 0, 0);
        }
    }

    float* ob = out + (size_t)b * CIN * SEQ;
#pragma unroll
    for (int i = 0; i < 4; ++i)
#pragma unroll
        for (int r = 0; r < 4; ++r) {
            const int o = w * 64 + i * 16 + q * 4 + r;
            ob[(size_t)o * SEQ + nt * 16 + c] = acc[i][r] + bias[o];
        }
}

extern "C" void kernel_launch(void* const* d_in, const int* in_sizes, int n_in,
                              void* d_out, int out_size, void* d_ws, size_t ws_size,
                              hipStream_t stream) {
    const float* x = (const float*)d_in[0];
    const float* w_qkv = (const float*)d_in[1];
    const float* w_out = (const float*)d_in[2];
    const float* b_out = (const float*)d_in[3];
    float* out = (float*)d_out;

    char* wsp = (char*)d_ws;
    short* qp  = (short*)wsp;                        // 8.39 MB
    short* kp  = (short*)(wsp + 8388608);            // 8.39 MB
    short* vp  = (short*)(wsp + 16777216);           // 8.39 MB
    short* aop = (short*)(wsp + 25165824);           // 8.39 MB
    short* wpk = (short*)(wsp + 33554432);           // 0.26 MB
    float* ssq = (float*)(wsp + 33816576);           // 32 KB
    short* xp  = (short*)(wsp + 33849344);           // 4.19 MB
    short* wqp = (short*)(wsp + 38043648);           // 0.79 MB (total 38.8 MB)

    pack_all<<<dim3(1281), 256, 0, stream>>>(x, w_qkv, w_out, xp, wqp, wpk, ssq);
    qkv_frag<<<dim3(768), 256, 0, stream>>>(xp, wqp, qp, kp, vp, ssq);
    attn_mfma<<<dim3(512), 256, 0, stream>>>(qp, kp, vp, ssq, aop);
    out_proj<<<dim3(64, 8), 256, 0, stream>>>(wpk, aop, b_out, out);
}